// Round 1
// baseline (477.605 us; speedup 1.0000x reference)
//
#include <hip/hip_runtime.h>
#include <hip/hip_bf16.h>
#include <math.h>

// Problem constants
#define SQ   4      // live sequences (b in 0..3, n == 0 only — output slice [:,0,-1,:])
#define LL   64     // sequence length
#define DM   128    // d_model
#define DI   256    // d_inner
#define DS   16     // d_state
#define RANK 8
#define ROWS (SQ*LL)   // 256 compact rows (s*64 + l)

// Workspace layout (float offsets)
#define WS_RESIDUAL 0          // 256*128
#define WS_XZ       32768      // 256*512
#define WS_U        163840     // 256*256
#define WS_DT       229376     // 256*256
#define WS_BC       294912     // 256*32
#define WS_Y        303104     // 256*256
// total 368640 floats = 1.44 MB

__device__ __forceinline__ float silu_f(float v) {
    return v / (1.0f + __expf(-v));
}

// ---------------------------------------------------------------------------
// kin: [layer 0: full MLP] or [layer>0: gate + out_proj(prev) ] + residual
//      + rmsnorm + in_proj.  32 wgs x 256 thr, 8 rows per wg.
// ---------------------------------------------------------------------------
__global__ __launch_bounds__(256) void kin_kernel(
    const float* __restrict__ mha_in,
    const float* __restrict__ mlp_w1, const float* __restrict__ mlp_b1,
    const float* __restrict__ mlp_w2, const float* __restrict__ mlp_b2,
    const float* __restrict__ in_proj_w, const float* __restrict__ out_proj_w,
    const float* __restrict__ blk_norm_w,
    float* __restrict__ ws, int layer)
{
    float* residual = ws + WS_RESIDUAL;
    float* xz       = ws + WS_XZ;
    float* ybuf     = ws + WS_Y;

    __shared__ float gated[8][256];   // layer0: cols 0..127 = x, 128..255 = h1
    __shared__ float res[8][128];
    __shared__ float hn[8][128];
    __shared__ float part[8][32];
    __shared__ float scale[8];

    const int tid  = threadIdx.x;
    const int row0 = blockIdx.x * 8;

    if (layer == 0) {
        // ---- load x rows (from mha_in[b,0,l,:]) ----
        for (int idx = tid; idx < 8*128; idx += 256) {
            int i = idx >> 7, c = idx & 127;
            int r = row0 + i; int s = r >> 6, l = r & 63;
            gated[i][c] = mha_in[(s*4096 + l)*128 + c];
        }
        __syncthreads();
        // ---- h1 = gelu(x @ w1^T + b1) -> gated[i][128+j] ----
        {
            int jg = tid & 63, rq = tid >> 6;
            int j0 = jg*2;
            float acc[2][2] = {{0.f,0.f},{0.f,0.f}};
            for (int k4 = 0; k4 < 32; ++k4) {
                float4 w0 = *(const float4*)&mlp_w1[(j0  )*128 + k4*4];
                float4 w1 = *(const float4*)&mlp_w1[(j0+1)*128 + k4*4];
                #pragma unroll
                for (int rr = 0; rr < 2; ++rr) {
                    float4 xv = *(const float4*)&gated[rq*2+rr][k4*4];
                    acc[rr][0] += xv.x*w0.x + xv.y*w0.y + xv.z*w0.z + xv.w*w0.w;
                    acc[rr][1] += xv.x*w1.x + xv.y*w1.y + xv.z*w1.z + xv.w*w1.w;
                }
            }
            #pragma unroll
            for (int rr = 0; rr < 2; ++rr)
                #pragma unroll
                for (int jj = 0; jj < 2; ++jj) {
                    float v = acc[rr][jj] + mlp_b1[j0+jj];
                    gated[rq*2+rr][128 + j0 + jj] = 0.5f*v*(1.0f + erff(v*0.70710678118f));
                }
        }
        __syncthreads();
        // ---- h2 = h1 @ w2^T + b2 -> res, residual = h2 ----
        {
            int jg = tid & 63, rq = tid >> 6;
            int j0 = jg*2;
            float acc[2][2] = {{0.f,0.f},{0.f,0.f}};
            for (int k4 = 0; k4 < 32; ++k4) {
                float4 w0 = *(const float4*)&mlp_w2[(j0  )*128 + k4*4];
                float4 w1 = *(const float4*)&mlp_w2[(j0+1)*128 + k4*4];
                #pragma unroll
                for (int rr = 0; rr < 2; ++rr) {
                    float4 xv = *(const float4*)&gated[rq*2+rr][128 + k4*4];
                    acc[rr][0] += xv.x*w0.x + xv.y*w0.y + xv.z*w0.z + xv.w*w0.w;
                    acc[rr][1] += xv.x*w1.x + xv.y*w1.y + xv.z*w1.z + xv.w*w1.w;
                }
            }
            #pragma unroll
            for (int rr = 0; rr < 2; ++rr) {
                int i = rq*2 + rr, r = row0 + i;
                #pragma unroll
                for (int jj = 0; jj < 2; ++jj) {
                    float v = acc[rr][jj] + mlp_b2[j0+jj];
                    res[i][j0+jj] = v;
                    residual[r*128 + j0 + jj] = v;
                }
            }
        }
    } else {
        // ---- gated = y_{l-1} * silu(z_{l-1}) ----
        for (int idx = tid; idx < 8*256; idx += 256) {
            int i = idx >> 8, dd = idx & 255;
            int r = row0 + i;
            float yv = ybuf[r*256 + dd];
            float zv = xz[r*512 + 256 + dd];
            gated[i][dd] = yv * silu_f(zv);
        }
        __syncthreads();
        // ---- h = gated @ out_w^T ; res = h + residual_old ; residual = res --
        {
            const float* ow = out_proj_w + (size_t)(layer-1)*128*256;
            int jg = tid & 63, rq = tid >> 6;
            int j0 = jg*2;
            float acc[2][2] = {{0.f,0.f},{0.f,0.f}};
            for (int k4 = 0; k4 < 64; ++k4) {
                float4 w0 = *(const float4*)&ow[(j0  )*256 + k4*4];
                float4 w1 = *(const float4*)&ow[(j0+1)*256 + k4*4];
                #pragma unroll
                for (int rr = 0; rr < 2; ++rr) {
                    float4 xv = *(const float4*)&gated[rq*2+rr][k4*4];
                    acc[rr][0] += xv.x*w0.x + xv.y*w0.y + xv.z*w0.z + xv.w*w0.w;
                    acc[rr][1] += xv.x*w1.x + xv.y*w1.y + xv.z*w1.z + xv.w*w1.w;
                }
            }
            #pragma unroll
            for (int rr = 0; rr < 2; ++rr) {
                int i = rq*2 + rr, r = row0 + i;
                #pragma unroll
                for (int jj = 0; jj < 2; ++jj) {
                    float v = acc[rr][jj] + residual[r*128 + j0 + jj];
                    res[i][j0+jj] = v;
                    residual[r*128 + j0 + jj] = v;
                }
            }
        }
    }
    __syncthreads();

    // ---- rmsnorm ----
    {
        int r = tid >> 5, lane = tid & 31;
        float sq = 0.f;
        #pragma unroll
        for (int t = 0; t < 4; ++t) { float v = res[r][lane + 32*t]; sq += v*v; }
        part[r][lane] = sq;
    }
    __syncthreads();
    if (tid < 8) {
        float sq = 0.f;
        #pragma unroll
        for (int t = 0; t < 32; ++t) sq += part[tid][t];
        scale[tid] = rsqrtf(sq * (1.0f/128.0f) + 1e-5f);
    }
    __syncthreads();
    {
        const float* bw = blk_norm_w + layer*128;
        for (int idx = tid; idx < 8*128; idx += 256) {
            int i = idx >> 7, c = idx & 127;
            hn[i][c] = res[i][c] * scale[i] * bw[c];
        }
    }
    __syncthreads();

    // ---- xz = hn @ in_w^T  (8 x 512, K=128) ----
    {
        const float* iw = in_proj_w + (size_t)layer*512*128;
        int jg = tid & 127, rh = tid >> 7;
        int j0 = jg*4;
        float acc[4][4] = {};
        for (int k4 = 0; k4 < 32; ++k4) {
            float4 w[4];
            #pragma unroll
            for (int jj = 0; jj < 4; ++jj)
                w[jj] = *(const float4*)&iw[(j0+jj)*128 + k4*4];
            #pragma unroll
            for (int rr = 0; rr < 4; ++rr) {
                float4 xv = *(const float4*)&hn[rh*4+rr][k4*4];
                #pragma unroll
                for (int jj = 0; jj < 4; ++jj)
                    acc[rr][jj] += xv.x*w[jj].x + xv.y*w[jj].y + xv.z*w[jj].z + xv.w*w[jj].w;
            }
        }
        #pragma unroll
        for (int rr = 0; rr < 4; ++rr) {
            int r = row0 + rh*4 + rr;
            float4 o; o.x = acc[rr][0]; o.y = acc[rr][1]; o.z = acc[rr][2]; o.w = acc[rr][3];
            *(float4*)&xz[r*512 + j0] = o;
        }
    }
}

// ---------------------------------------------------------------------------
// kmid: conv1d + silu -> u ; x_proj -> (dt_pre, B, C) ; dt = softplus
// 16 wgs (4 per seq, 16 rows each) x 256 thr
// ---------------------------------------------------------------------------
__global__ __launch_bounds__(256) void kmid_kernel(
    const float* __restrict__ conv_w, const float* __restrict__ conv_b,
    const float* __restrict__ x_proj_w,
    const float* __restrict__ dt_proj_w, const float* __restrict__ dt_proj_b,
    float* __restrict__ ws, int layer)
{
    float* xz    = ws + WS_XZ;
    float* ubuf  = ws + WS_U;
    float* dtbuf = ws + WS_DT;
    float* bc    = ws + WS_BC;

    __shared__ float uL[16][256];
    __shared__ float xdbl[16][40];

    const int tid = threadIdx.x;
    const int s  = blockIdx.x >> 2;
    const int lb = blockIdx.x & 3;
    const int l0 = lb*16;
    const int r0 = s*64 + l0;

    // ---- phase 1: causal conv (width 4) + silu ----
    {
        int d = tid;
        const float* cw = conv_w + (size_t)(layer*256 + d)*4;
        float w0 = cw[0], w1 = cw[1], w2 = cw[2], w3 = cw[3];
        float b  = conv_b[layer*256 + d];
        float xm3 = (l0-3 >= 0) ? xz[(s*64 + l0-3)*512 + d] : 0.f;
        float xm2 = (l0-2 >= 0) ? xz[(s*64 + l0-2)*512 + d] : 0.f;
        float xm1 = (l0-1 >= 0) ? xz[(s*64 + l0-1)*512 + d] : 0.f;
        for (int l = 0; l < 16; ++l) {
            float x0 = xz[(r0 + l)*512 + d];
            float v  = b + w0*xm3 + w1*xm2 + w2*xm1 + w3*x0;
            float u  = silu_f(v);
            uL[l][d] = u;
            ubuf[(r0+l)*256 + d] = u;
            xm3 = xm2; xm2 = xm1; xm1 = x0;
        }
    }
    __syncthreads();

    // ---- phase 2: x_dbl = u @ x_proj_w^T  (16 x 40, K=256) ----
    {
        int l = tid >> 4, jg = tid & 15;
        if (jg < 10) {
            int j0 = jg*4;
            const float* xw = x_proj_w + (size_t)layer*40*256;
            float acc[4] = {0.f,0.f,0.f,0.f};
            for (int k4 = 0; k4 < 64; ++k4) {
                float4 uv = *(const float4*)&uL[l][k4*4];
                #pragma unroll
                for (int jj = 0; jj < 4; ++jj) {
                    float4 w = *(const float4*)&xw[(j0+jj)*256 + k4*4];
                    acc[jj] += uv.x*w.x + uv.y*w.y + uv.z*w.z + uv.w*w.w;
                }
            }
            #pragma unroll
            for (int jj = 0; jj < 4; ++jj) xdbl[l][j0+jj] = acc[jj];
        }
    }
    __syncthreads();

    // ---- phase 3: dt = softplus(x_dbl[:, :8] @ dt_w^T + dt_b) ----
    {
        int d = tid;
        const float* dw = dt_proj_w + (size_t)(layer*256 + d)*8;
        float w[8];
        #pragma unroll
        for (int t = 0; t < 8; ++t) w[t] = dw[t];
        float b = dt_proj_b[layer*256 + d];
        for (int l = 0; l < 16; ++l) {
            float pre = b;
            #pragma unroll
            for (int t = 0; t < 8; ++t) pre += xdbl[l][t]*w[t];
            float sp = (pre > 20.f) ? pre : log1pf(__expf(pre));
            dtbuf[(r0+l)*256 + d] = sp;
        }
    }

    // ---- phase 4: pack B,C ----
    for (int idx = tid; idx < 16*32; idx += 256) {
        int l = idx >> 5, c = idx & 31;
        bc[(r0+l)*32 + c] = xdbl[l][8 + c];
    }
}

// ---------------------------------------------------------------------------
// kscan: sequential selective scan. 16 wgs (4 per seq, 64 channels each),
// 4 threads per channel (4 states each), shfl reduce.
// ---------------------------------------------------------------------------
__global__ __launch_bounds__(256) void kscan_kernel(
    const float* __restrict__ A_log, const float* __restrict__ D_skip,
    float* __restrict__ ws, int layer)
{
    float* ubuf  = ws + WS_U;
    float* dtbuf = ws + WS_DT;
    float* bc    = ws + WS_BC;
    float* ybuf  = ws + WS_Y;

    const int tid = threadIdx.x;
    const int s  = blockIdx.x >> 2;
    const int db = blockIdx.x & 3;
    const int dloc = tid >> 2, sub = tid & 3;
    const int d = db*64 + dloc;

    float A[4], h[4] = {0.f,0.f,0.f,0.f};
    #pragma unroll
    for (int j = 0; j < 4; ++j)
        A[j] = -__expf(A_log[(size_t)(layer*256 + d)*16 + sub*4 + j]);
    float Dsk = D_skip[layer*256 + d];

    const int base = s*64;
    float dtv = dtbuf[base*256 + d];
    float uv  = ubuf[base*256 + d];
    float4 B4 = *(const float4*)&bc[base*32 + sub*4];
    float4 C4 = *(const float4*)&bc[base*32 + 16 + sub*4];

    for (int l = 0; l < 64; ++l) {
        float dtn = 0.f, un = 0.f; float4 Bn = {0,0,0,0}, Cn = {0,0,0,0};
        if (l < 63) {
            int rn = base + l + 1;
            dtn = dtbuf[rn*256 + d];
            un  = ubuf[rn*256 + d];
            Bn  = *(const float4*)&bc[rn*32 + sub*4];
            Cn  = *(const float4*)&bc[rn*32 + 16 + sub*4];
        }
        float du = dtv * uv;
        float yp = 0.f, dA;
        dA = __expf(dtv*A[0]); h[0] = dA*h[0] + du*B4.x; yp += h[0]*C4.x;
        dA = __expf(dtv*A[1]); h[1] = dA*h[1] + du*B4.y; yp += h[1]*C4.y;
        dA = __expf(dtv*A[2]); h[2] = dA*h[2] + du*B4.z; yp += h[2]*C4.z;
        dA = __expf(dtv*A[3]); h[3] = dA*h[3] + du*B4.w; yp += h[3]*C4.w;
        yp += __shfl_xor(yp, 1);
        yp += __shfl_xor(yp, 2);
        if (sub == 0) ybuf[(base+l)*256 + d] = yp + uv*Dsk;
        dtv = dtn; uv = un; B4 = Bn; C4 = Cn;
    }
}

// ---------------------------------------------------------------------------
// kfin: last-layer gate + out_proj for the 4 needed rows (l=63) + final
// residual + rmsnorm + key_valid mask. 1 wg x 256 thr.
// ---------------------------------------------------------------------------
__global__ __launch_bounds__(256) void kfin_kernel(
    const float* __restrict__ out_proj_w, const float* __restrict__ norm_f_w,
    const int* __restrict__ mask,
    float* __restrict__ ws, float* __restrict__ out)
{
    float* residual = ws + WS_RESIDUAL;
    float* xz       = ws + WS_XZ;
    float* ybuf     = ws + WS_Y;

    __shared__ float gated[4][256];
    __shared__ float resf[4][128];
    __shared__ float part[4][32];
    __shared__ float scale[4];
    __shared__ int validL[4];

    const int tid = threadIdx.x;
    if (tid < 4) validL[tid] = 0;
    __syncthreads();
    {
        int s = tid >> 6, l = tid & 63;
        if (mask[s*4096 + l] != 0) validL[s] = 1;   // benign race, same value
    }
    for (int idx = tid; idx < 4*256; idx += 256) {
        int si = idx >> 8, dd = idx & 255;
        int row = si*64 + 63;
        float yv = ybuf[row*256 + dd];
        float zv = xz[row*512 + 256 + dd];
        gated[si][dd] = yv * silu_f(zv);
    }
    __syncthreads();
    {
        const float* ow = out_proj_w + (size_t)3*128*256;
        int jj = tid & 127, sh = tid >> 7;   // rows sh, sh+2
        float acc[2] = {0.f, 0.f};
        for (int k4 = 0; k4 < 64; ++k4) {
            float4 w = *(const float4*)&ow[jj*256 + k4*4];
            #pragma unroll
            for (int rr = 0; rr < 2; ++rr) {
                float4 g = *(const float4*)&gated[sh + rr*2][k4*4];
                acc[rr] += g.x*w.x + g.y*w.y + g.z*w.z + g.w*w.w;
            }
        }
        #pragma unroll
        for (int rr = 0; rr < 2; ++rr) {
            int si = sh + rr*2;
            int row = si*64 + 63;
            resf[si][jj] = acc[rr] + residual[row*128 + jj];
        }
    }
    __syncthreads();
    if (tid < 128) {
        int r = tid >> 5, lane = tid & 31;
        float sq = 0.f;
        #pragma unroll
        for (int t = 0; t < 4; ++t) { float v = resf[r][lane + 32*t]; sq += v*v; }
        part[r][lane] = sq;
    }
    __syncthreads();
    if (tid < 4) {
        float sq = 0.f;
        #pragma unroll
        for (int t = 0; t < 32; ++t) sq += part[tid][t];
        scale[tid] = rsqrtf(sq * (1.0f/128.0f) + 1e-5f);
    }
    __syncthreads();
    for (int idx = tid; idx < 512; idx += 256) {
        int si = idx >> 7, c = idx & 127;
        float v = resf[si][c] * scale[si] * norm_f_w[c];
        out[si*128 + c] = validL[si] ? v : 0.f;
    }
}

// ---------------------------------------------------------------------------
extern "C" void kernel_launch(void* const* d_in, const int* in_sizes, int n_in,
                              void* d_out, int out_size, void* d_ws, size_t ws_size,
                              hipStream_t stream) {
    const float* mha_in     = (const float*)d_in[0];
    const int*   mask       = (const int*)  d_in[1];
    const float* mlp_w1     = (const float*)d_in[2];
    const float* mlp_b1     = (const float*)d_in[3];
    const float* mlp_w2     = (const float*)d_in[4];
    const float* mlp_b2     = (const float*)d_in[5];
    const float* in_proj_w  = (const float*)d_in[6];
    const float* conv_w     = (const float*)d_in[7];
    const float* conv_b     = (const float*)d_in[8];
    const float* x_proj_w   = (const float*)d_in[9];
    const float* dt_proj_w  = (const float*)d_in[10];
    const float* dt_proj_b  = (const float*)d_in[11];
    const float* A_log      = (const float*)d_in[12];
    const float* D_skip     = (const float*)d_in[13];
    const float* out_proj_w = (const float*)d_in[14];
    const float* blk_norm_w = (const float*)d_in[15];
    const float* norm_f_w   = (const float*)d_in[16];
    float* ws  = (float*)d_ws;
    float* out = (float*)d_out;

    for (int layer = 0; layer < 4; ++layer) {
        kin_kernel<<<32, 256, 0, stream>>>(mha_in, mlp_w1, mlp_b1, mlp_w2, mlp_b2,
                                           in_proj_w, out_proj_w, blk_norm_w, ws, layer);
        kmid_kernel<<<16, 256, 0, stream>>>(conv_w, conv_b, x_proj_w,
                                            dt_proj_w, dt_proj_b, ws, layer);
        kscan_kernel<<<16, 256, 0, stream>>>(A_log, D_skip, ws, layer);
    }
    kfin_kernel<<<1, 256, 0, stream>>>(out_proj_w, norm_f_w, mask, ws, out);
}